// Round 8
// baseline (211.932 us; speedup 1.0000x reference)
//
#include <hip/hip_runtime.h>
#include <stdint.h>

#define L_SEQ 2048
#define B_SZ 2
#define NHH 8
#define HDD 128
#define C_SZ 1024
#define EMB_D 33
#define ORD 64
#define BANDS 16
#define FSTRIDE (L_SEQ + 256)   // 256 leading zeros per filter row for causal masking
#define FRS_S 2600              // FRS row stride in f16: 5200B == 80 mod 1024 -> a-windows tile banks
#define FRS_FILL 2176           // only [0,2176) is ever read (max z+7 = 2167)

typedef _Float16 f16;
typedef f16 f16x8 __attribute__((ext_vector_type(8)));
typedef f16 f16x4 __attribute__((ext_vector_type(4)));
typedef float f32x4 __attribute__((ext_vector_type(4)));

// ---------------------------------------------------------------------------
// Kernel 1: hyena filter MLP -> filt[hd][FSTRIDE] f32 (row = 256 zeros | 2048 taps)
// filt[hd][lag 0] += D[hd]  (absorbs the kv*D term).
// ---------------------------------------------------------------------------
__global__ void filter_kernel(const float* __restrict__ w0, const float* __restrict__ b0,
                              const float* __restrict__ w1, const float* __restrict__ b1,
                              const float* __restrict__ w2, const float* __restrict__ b2,
                              const float* __restrict__ fr, const float* __restrict__ wf,
                              const float* __restrict__ md, const float* __restrict__ Dv,
                              float* __restrict__ filt) {
  int tid = threadIdx.x;
  int o = tid & 63;
  int lq = tid >> 6;                 // 0..3
  int l = blockIdx.x * 4 + lq;

  if (blockIdx.x < 128) filt[(size_t)blockIdx.x * FSTRIDE + tid] = 0.0f;

  __shared__ float zs[4][EMB_D];
  __shared__ float hs[4][ORD];
  __shared__ float gs[4][ORD];

  float t = (float)l / (float)(L_SEQ - 1);
  float wang = 6.2831853071795864f * (float)l / (float)L_SEQ;
  const float fstep = (15.0f - 1e-4f) / 15.0f;

  if (o == 0) zs[lq][0] = t;
  if (o >= 1 && o < 1 + BANDS) {
    int j = o - 1;
    float fj = 1e-4f + fstep * (float)j;
    zs[lq][1 + j] = cosf(wang * fj);
  }
  if (o >= 1 + BANDS && o < 1 + 2 * BANDS) {
    int j = o - 1 - BANDS;
    float fj = 1e-4f + fstep * (float)j;
    zs[lq][1 + BANDS + j] = -sinf(wang * fj);
  }
  __syncthreads();

  float fo = fr[o];
  float a = b0[o];
  for (int e = 0; e < EMB_D; ++e) a += zs[lq][e] * w0[o * EMB_D + e];
  hs[lq][o] = sinf(fo * a);
  __syncthreads();

  a = b1[o];
  for (int e = 0; e < ORD; ++e) a += hs[lq][e] * w1[o * ORD + e];
  gs[lq][o] = sinf(fo * a);
  __syncthreads();

  a = b2[o];
  for (int e = 0; e < ORD; ++e) a += gs[lq][e] * w2[o * ORD + e];
  float h3 = sinf(fo * a);
  __syncthreads();
  hs[lq][o] = h3;
  __syncthreads();

  #pragma unroll
  for (int pass = 0; pass < 2; ++pass) {
    int hd = pass * 64 + o;
    float acc = 0.0f;
    for (int e = 0; e < ORD; ++e) acc += hs[lq][e] * wf[hd * ORD + e];
    float val = acc * expf(-t * fabsf(md[hd]));
    if (l == 0) val += Dv[hd];   // absorb D term into lag-0 tap
    filt[(size_t)hd * FSTRIDE + 256 + l] = val;
  }
}

// ---------------------------------------------------------------------------
// Kernel 2: depthwise causal 3-tap conv + layout transform.
// q -> AqT[b][hd][n1][l]  (TRANSPOSED: epilogue reads float4 runs of l)
// k,v -> A[b][hd][l][n1]  (staging reads runs of m at fixed n)
// ---------------------------------------------------------------------------
#define TLC 64
__global__ void shortconv_kernel(const float* __restrict__ q_in,
                                 const float* __restrict__ k_in,
                                 const float* __restrict__ v_in,
                                 const float* __restrict__ scw,
                                 const float* __restrict__ scb,
                                 float* __restrict__ AqT, float* __restrict__ Ak,
                                 float* __restrict__ Av) {
  int bid = blockIdx.x;
  int lt = bid & 31;
  int np = (bid >> 5) & 7;
  int b = bid >> 8;
  int l0 = lt * TLC;
  int tid = threadIdx.x;

  __shared__ float xs[TLC + 2][HDD + 4];
  __shared__ float wcs[HDD][4];

  const float* ins[3] = {q_in, k_in, v_in};
  float* outs[3] = {AqT, Ak, Av};

  for (int tsr = 0; tsr < 3; ++tsr) {
    const float* x = ins[tsr];
    if (tid < HDD) {
      int c = np * HDD + tid;
      wcs[tid][0] = scw[(tsr * C_SZ + c) * 3 + 0];
      wcs[tid][1] = scw[(tsr * C_SZ + c) * 3 + 1];
      wcs[tid][2] = scw[(tsr * C_SZ + c) * 3 + 2];
      wcs[tid][3] = scb[tsr * C_SZ + c];
    }
    for (int idx = tid; idx < (TLC + 2) * HDD; idx += 256) {
      int row = idx >> 7, hn = idx & 127;
      int l = l0 - 2 + row;
      float val = 0.0f;
      if (l >= 0) val = x[(((size_t)l * B_SZ + b) * NHH + np) * HDD + hn];
      xs[row][hn] = val;
    }
    __syncthreads();

    int n1 = tid & 7;
    int lp = tid >> 3;
    float* outp = outs[tsr];
    for (int hdi = 0; hdi < 16; ++hdi) {
      int hn = hdi * 8 + n1;
      float cw0 = wcs[hn][0], cw1 = wcs[hn][1], cw2 = wcs[hn][2], cb = wcs[hn][3];
      int hd = np * 16 + hdi;
      #pragma unroll
      for (int half = 0; half < 2; ++half) {
        int ll = half * 32 + lp;
        float y = cb + cw0 * xs[ll][hn] + cw1 * xs[ll + 1][hn]
                     + cw2 * xs[ll + 2][hn];
        if (tsr == 0)   // transposed
          outp[(((size_t)b * HDD + hd) * NHH + n1) * L_SEQ + (l0 + ll)] = y;
        else
          outp[(((size_t)b * HDD + hd) * L_SEQ + (l0 + ll)) * NHH + n1] = y;
      }
    }
    __syncthreads();
  }
}

// ---------------------------------------------------------------------------
// Kernel 3 (MFMA v3): per (b,hd):
//   G[l,n] = sum_{m<=l} W[l-m] * U[m,n],  U[m,n1*8+n2] = Av[m,n1]*Ak[m,n2]
//   out[l,n2] = sum_n1 Aq[l,n1] * G[l,n1*8+n2]
// vs v2: (1) FRS stride 2600 f16 (5200B = 80 mod 1024) -> af shift-copy
// windows tile the bank space, killing the 8-way af conflicts; (2) Avt/Akt
// re-laid as [s][y][p*8+e] -> vf reads are one 128B row (conflict-free),
// kf/writes at the volume floor; (3) Qt LDS removed -> epilogue reads AqT
// (transposed in kernel 2) from global/L1.  LDS 61.4 -> 49.8 KB.
// mfma_f32_16x16x32_f16: A row=lane&15, k=(lane>>4)*8+e; B col=lane&15,
// k=(lane>>4)*8+e; C/D col=lane&15, row=(lane>>4)*4+reg.  (verified R6/R7)
// ---------------------------------------------------------------------------
__global__ void __launch_bounds__(256, 2)
hyena_main(const float* __restrict__ AqT, const float* __restrict__ Ak,
           const float* __restrict__ Av, const float* __restrict__ filt,
           float* __restrict__ out) {
  int bid = blockIdx.x;            // 512 = B * HD * 2
  int g  = bid & 1;
  int hd = (bid >> 1) & 127;
  int b  = bid >> 8;
  int tid = threadIdx.x;
  int w = tid >> 6;                // wave 0..3
  int lane = tid & 63;
  int r = lane & 15;               // A row / B col within 16
  int p = lane >> 4;               // k part 0..3
  int a = (15 - r) & 7;            // FRS shift-copy class

  __shared__ f16 FRS[8][FRS_S];        // FRS[a][z] = W[2047 - z - a]
  __shared__ f16 Avt[2][4][8][32];     // [buf][s][n1][p*8+e]
  __shared__ f16 Akt[2][4][8][32];     // [buf][s][n2][p*8+e]

  const float* frow = filt + (size_t)hd * FSTRIDE + 256;   // lag-0
  size_t base = ((size_t)b * HDD + hd) * (size_t)L_SEQ * NHH;
  const float* avb = Av + base;
  const float* akb = Ak + base;
  const float* aqtb = AqT + ((size_t)b * HDD + hd) * NHH * L_SEQ;
  int np = hd >> 4, hnb = (hd & 15) * 8;

  // ---- stage FRS once; frow[-256..2047] is valid (zero pad in front)
  for (int idx = tid; idx < 8 * FRS_FILL; idx += 256) {
    int aa = idx / FRS_FILL;
    int z  = idx - aa * FRS_FILL;
    FRS[aa][z] = (f16)frow[2047 - z - aa];
  }

  f32x4 acc[8][4];
  // staging decode: thread -> (y, h, pp, ss); m_loc = ss*32+pp*8+h*4
  int sy = tid & 7, sh = (tid >> 3) & 1, sp = (tid >> 4) & 3, ss = tid >> 6;
  int m_base = ss * 32 + sp * 8 + sh * 4;
  float rA[4], rK[4];

  auto stage_load = [&](int c) {
    const float* sa = avb + (size_t)(c * 128 + m_base) * 8 + sy;
    const float* sk = akb + (size_t)(c * 128 + m_base) * 8 + sy;
    rA[0] = sa[0]; rA[1] = sa[8]; rA[2] = sa[16]; rA[3] = sa[24];
    rK[0] = sk[0]; rK[1] = sk[8]; rK[2] = sk[16]; rK[3] = sk[24];
  };
  auto stage_write = [&](int bi) {
    f16x4 va = {(f16)rA[0], (f16)rA[1], (f16)rA[2], (f16)rA[3]};
    f16x4 vk = {(f16)rK[0], (f16)rK[1], (f16)rK[2], (f16)rK[3]};
    *(f16x4*)&Avt[bi][ss][sy][sp * 8 + sh * 4] = va;
    *(f16x4*)&Akt[bi][ss][sy][sp * 8 + sh * 4] = vk;
  };

  auto unit = [&](int lt, int c, int bi) {
    int dy = 2047 - (lt - c) * 128;
    int zbase = dy - r - a + p * 8 - 112;     // f[dd] <-> d = dd-7; 8-aligned
    f16x8 f[14];
    #pragma unroll
    for (int dd = 0; dd < 14; ++dd)
      f[dd] = *(const f16x8*)&FRS[a][zbase + 16 * dd];
    #pragma unroll
    for (int s = 0; s < 4; ++s) {
      f16x8 kf = *(const f16x8*)&Akt[bi][s][r & 7][p * 8];
      #pragma unroll
      for (int nt = 0; nt < 4; ++nt) {
        f16x8 vf = *(const f16x8*)&Avt[bi][s][nt * 2 + (r >> 3)][p * 8];
        f16x8 bf = vf * kf;                    // v_pk_mul_f16
        #pragma unroll
        for (int mt = 0; mt < 8; ++mt)
          acc[mt][nt] = __builtin_amdgcn_mfma_f32_16x16x32_f16(
              f[7 + 2 * s - mt], bf, acc[mt][nt], 0, 0, 0);
      }
    }
  };

  auto epilogue = [&](int lt) {
    int l0 = lt * 128;
    int hi = r >> 3;
    int n2 = r & 7;
    #pragma unroll
    for (int mt = 0; mt < 8; ++mt) {
      float4 qv[4];
      #pragma unroll
      for (int nt = 0; nt < 4; ++nt)
        qv[nt] = *(const float4*)(aqtb + (size_t)(nt * 2 + hi) * L_SEQ
                                  + l0 + mt * 16 + p * 4);
      #pragma unroll
      for (int reg = 0; reg < 4; ++reg) {
        float pr = qv[0][reg] * acc[mt][0][reg] + qv[1][reg] * acc[mt][1][reg]
                 + qv[2][reg] * acc[mt][2][reg] + qv[3][reg] * acc[mt][3][reg];
        pr += __shfl_xor(pr, 8, 64);
        if (r < 8) {
          int i = mt * 16 + p * 4 + reg;
          out[(((size_t)b * NHH + np) * L_SEQ + (l0 + i)) * HDD + hnb + n2] = pr;
        }
      }
    }
  };

  auto run_pass = [&](int mytile, int NC) {
    #pragma unroll
    for (int mt = 0; mt < 8; ++mt)
      #pragma unroll
      for (int nt = 0; nt < 4; ++nt)
        acc[mt][nt] = f32x4{0.f, 0.f, 0.f, 0.f};
    stage_load(0);
    for (int c = 0; c < NC; ++c) {
      stage_write(c & 1);
      __syncthreads();                 // buf c&1 ready; units(c-1) all done
      if (c + 1 < NC) stage_load(c + 1);   // global latency hides under unit(c)
      if (mytile >= c) unit(mytile, c, c & 1);
      if (mytile == c) epilogue(mytile);
    }
    __syncthreads();
  };

  // pass A: tiles g*4+w (NC = g*4+4); pass B: tiles 15-g*4-w (NC = 16-g*4)
  run_pass(g * 4 + w, g * 4 + 4);
  run_pass(15 - g * 4 - w, 16 - g * 4);
}

// ---------------------------------------------------------------------------
extern "C" void kernel_launch(void* const* d_in, const int* in_sizes, int n_in,
                              void* d_out, int out_size, void* d_ws, size_t ws_size,
                              hipStream_t stream) {
  const float* q_in = (const float*)d_in[0];
  const float* k_in = (const float*)d_in[1];
  const float* v_in = (const float*)d_in[2];
  const float* scw  = (const float*)d_in[3];
  const float* scb  = (const float*)d_in[4];
  const float* Dv   = (const float*)d_in[5];
  const float* w0   = (const float*)d_in[6];
  const float* b0   = (const float*)d_in[7];
  const float* w1   = (const float*)d_in[8];
  const float* b1   = (const float*)d_in[9];
  const float* w2   = (const float*)d_in[10];
  const float* b2   = (const float*)d_in[11];
  const float* fr   = (const float*)d_in[12];
  const float* wf   = (const float*)d_in[13];
  const float* md   = (const float*)d_in[14];

  float* ws   = (float*)d_ws;
  float* filt = ws;                                        // 128*2304 f32
  float* AqT  = ws + (size_t)HDD * FSTRIDE;                // each 2*128*2048*8 f32
  float* Ak   = AqT + (size_t)B_SZ * HDD * L_SEQ * NHH;
  float* Av   = Ak + (size_t)B_SZ * HDD * L_SEQ * NHH;

  filter_kernel<<<512, 256, 0, stream>>>(w0, b0, w1, b1, w2, b2, fr, wf, md, Dv, filt);
  shortconv_kernel<<<512, 256, 0, stream>>>(q_in, k_in, v_in, scw, scb, AqT, Ak, Av);
  hyena_main<<<512, 256, 0, stream>>>(AqT, Ak, Av, filt, (float*)d_out);
}

// Round 9
// 156.632 us; speedup vs baseline: 1.3531x; 1.3531x over previous
//
#include <hip/hip_runtime.h>
#include <stdint.h>

#define L_SEQ 2048
#define B_SZ 2
#define NHH 8
#define HDD 128
#define C_SZ 1024
#define EMB_D 33
#define ORD 64
#define BANDS 16
#define FSTRIDE (L_SEQ + 256)   // 256 leading zeros per filter row for causal masking
#define FRS_S 2600              // FRS row stride (f16)
#define FRS_FILL 2176           // z in [0,2176) is the read range
#define QTS 136                 // Qt inner stride (f32)

typedef _Float16 f16;
typedef f16 f16x8 __attribute__((ext_vector_type(8)));
typedef float f32x4 __attribute__((ext_vector_type(4)));

// ---------------------------------------------------------------------------
// Kernel 1: hyena filter MLP -> filt[hd][FSTRIDE] f32 (row = 256 zeros | 2048 taps)
// filt[hd][lag 0] += D[hd]  (absorbs the kv*D term).
// ---------------------------------------------------------------------------
__global__ void filter_kernel(const float* __restrict__ w0, const float* __restrict__ b0,
                              const float* __restrict__ w1, const float* __restrict__ b1,
                              const float* __restrict__ w2, const float* __restrict__ b2,
                              const float* __restrict__ fr, const float* __restrict__ wf,
                              const float* __restrict__ md, const float* __restrict__ Dv,
                              float* __restrict__ filt) {
  int tid = threadIdx.x;
  int o = tid & 63;
  int lq = tid >> 6;                 // 0..3
  int l = blockIdx.x * 4 + lq;

  if (blockIdx.x < 128) filt[(size_t)blockIdx.x * FSTRIDE + tid] = 0.0f;

  __shared__ float zs[4][EMB_D];
  __shared__ float hs[4][ORD];
  __shared__ float gs[4][ORD];

  float t = (float)l / (float)(L_SEQ - 1);
  float wang = 6.2831853071795864f * (float)l / (float)L_SEQ;
  const float fstep = (15.0f - 1e-4f) / 15.0f;

  if (o == 0) zs[lq][0] = t;
  if (o >= 1 && o < 1 + BANDS) {
    int j = o - 1;
    float fj = 1e-4f + fstep * (float)j;
    zs[lq][1 + j] = cosf(wang * fj);
  }
  if (o >= 1 + BANDS && o < 1 + 2 * BANDS) {
    int j = o - 1 - BANDS;
    float fj = 1e-4f + fstep * (float)j;
    zs[lq][1 + BANDS + j] = -sinf(wang * fj);
  }
  __syncthreads();

  float fo = fr[o];
  float a = b0[o];
  for (int e = 0; e < EMB_D; ++e) a += zs[lq][e] * w0[o * EMB_D + e];
  hs[lq][o] = sinf(fo * a);
  __syncthreads();

  a = b1[o];
  for (int e = 0; e < ORD; ++e) a += hs[lq][e] * w1[o * ORD + e];
  gs[lq][o] = sinf(fo * a);
  __syncthreads();

  a = b2[o];
  for (int e = 0; e < ORD; ++e) a += gs[lq][e] * w2[o * ORD + e];
  float h3 = sinf(fo * a);
  __syncthreads();
  hs[lq][o] = h3;
  __syncthreads();

  #pragma unroll
  for (int pass = 0; pass < 2; ++pass) {
    int hd = pass * 64 + o;
    float acc = 0.0f;
    for (int e = 0; e < ORD; ++e) acc += hs[lq][e] * wf[hd * ORD + e];
    float val = acc * expf(-t * fabsf(md[hd]));
    if (l == 0) val += Dv[hd];   // absorb D term into lag-0 tap
    filt[(size_t)hd * FSTRIDE + 256 + l] = val;
  }
}

// ---------------------------------------------------------------------------
// Kernel 2: depthwise causal 3-tap conv + layout transform.
// q -> Aq[b][hd][l][n1]  f32 (R7 layout, coalesced, for Qt staging)
// k -> Akt16, v -> Avt16: chunk-blocked swizzled f16 tiles
//   [b][hd][chunk=l>>7][2048B tile]; element (n, m=l&127) at byte
//   n*256 + ((m*2) ^ (n<<4))   -> kernel-3 DMA-stages tiles linearly.
// ---------------------------------------------------------------------------
#define TLC 64
__global__ void shortconv_kernel(const float* __restrict__ q_in,
                                 const float* __restrict__ k_in,
                                 const float* __restrict__ v_in,
                                 const float* __restrict__ scw,
                                 const float* __restrict__ scb,
                                 float* __restrict__ Aq, f16* __restrict__ Akt16,
                                 f16* __restrict__ Avt16) {
  int bid = blockIdx.x;
  int lt = bid & 31;
  int np = (bid >> 5) & 7;
  int b = bid >> 8;
  int l0 = lt * TLC;
  int tid = threadIdx.x;

  __shared__ float xs[TLC + 2][HDD + 4];
  __shared__ float wcs[HDD][4];

  const float* ins[3] = {q_in, k_in, v_in};

  for (int tsr = 0; tsr < 3; ++tsr) {
    const float* x = ins[tsr];
    if (tid < HDD) {
      int c = np * HDD + tid;
      wcs[tid][0] = scw[(tsr * C_SZ + c) * 3 + 0];
      wcs[tid][1] = scw[(tsr * C_SZ + c) * 3 + 1];
      wcs[tid][2] = scw[(tsr * C_SZ + c) * 3 + 2];
      wcs[tid][3] = scb[tsr * C_SZ + c];
    }
    for (int idx = tid; idx < (TLC + 2) * HDD; idx += 256) {
      int row = idx >> 7, hn = idx & 127;
      int l = l0 - 2 + row;
      float val = 0.0f;
      if (l >= 0) val = x[(((size_t)l * B_SZ + b) * NHH + np) * HDD + hn];
      xs[row][hn] = val;
    }
    __syncthreads();

    int n1 = tid & 7;
    int lp = tid >> 3;
    for (int hdi = 0; hdi < 16; ++hdi) {
      int hn = hdi * 8 + n1;
      float cw0 = wcs[hn][0], cw1 = wcs[hn][1], cw2 = wcs[hn][2], cb = wcs[hn][3];
      int hd = np * 16 + hdi;
      #pragma unroll
      for (int half = 0; half < 2; ++half) {
        int ll = half * 32 + lp;
        float y = cb + cw0 * xs[ll][hn] + cw1 * xs[ll + 1][hn]
                     + cw2 * xs[ll + 2][hn];
        int l = l0 + ll;
        if (tsr == 0) {
          Aq[(((size_t)b * HDD + hd) * L_SEQ + l) * NHH + n1] = y;
        } else {
          int ch = l >> 7, m = l & 127;
          int off = (n1 << 8) | ((m << 1) ^ (n1 << 4));   // swizzled byte in tile
          char* base = (tsr == 1) ? (char*)Akt16 : (char*)Avt16;
          *(f16*)(base + ((((size_t)(b * HDD + hd)) * 16 + ch) << 11) + off) = (f16)y;
        }
      }
    }
    __syncthreads();
  }
}

// ---------------------------------------------------------------------------
// Kernel 3 (MFMA v4): per (b,hd):
//   G[l,n] = sum_{m<=l} W[l-m] * U[m,n],  U[m,n1*8+n2] = Av[m,n1]*Ak[m,n2]
//   out[l,n2] = sum_n1 Aq[l,n1] * G[l,n1*8+n2]
// vs v3: staging via global_load_lds DMA of pre-swizzled 2KB f16 tiles
// (1 instr/wave/chunk; removes 16 scalar loads + vmcnt(0) chain + f32->f16
// VALU + LDS write conflicts). vf reads conflict-free via n-XOR swizzle;
// kf 4-way (4 reads/unit). Qt epilogue restored (R7, passing).
// mfma_f32_16x16x32_f16: A row=lane&15, k=(lane>>4)*8+e; B col=lane&15,
// k=(lane>>4)*8+e; C/D col=lane&15, row=(lane>>4)*4+reg.  (verified R6-R8)
// ---------------------------------------------------------------------------
__global__ void __launch_bounds__(256, 2)
hyena_main(const float* __restrict__ Aq, const f16* __restrict__ Akt16,
           const f16* __restrict__ Avt16, const float* __restrict__ filt,
           float* __restrict__ out) {
  int bid = blockIdx.x;            // 512 = B * HD * 2
  int g  = bid & 1;
  int hd = (bid >> 1) & 127;
  int b  = bid >> 8;
  int tid = threadIdx.x;
  int w = tid >> 6;                // wave 0..3
  int lane = tid & 63;
  int r = lane & 15;               // A row / B col within 16
  int p = lane >> 4;               // k part 0..3
  int a = (15 - r) & 7;            // FRS shift-copy class

  __shared__ f16 FRS[8][FRS_S];    // FRS[a][z] = W[2047 - z - a]   (41600 B)
  __shared__ f16 AV[2][1024];      // swizzled [8n][128m] tile, dbuf (4 KB)
  __shared__ f16 AK[2][1024];      //                                (4 KB)
  __shared__ float Qt[4][8][QTS];  // per-wave Q tile               (17408 B)

  const float* frow = filt + (size_t)hd * FSTRIDE + 256;   // lag-0
  const float* aqb = Aq + ((size_t)b * HDD + hd) * (size_t)L_SEQ * NHH;
  const char* avtg = (const char*)Avt16 + (((size_t)(b * HDD + hd)) * 16 << 11);
  const char* aktg = (const char*)Akt16 + (((size_t)(b * HDD + hd)) * 16 << 11);
  int np = hd >> 4, hnb = (hd & 15) * 8;

  // ---- stage FRS once (no integer div); frow[-256..2047] valid (zero pad)
  for (int aa = 0; aa < 8; ++aa)
    for (int z = tid; z < FRS_FILL; z += 256)
      FRS[aa][z] = (f16)frow[2047 - z - aa];

  f32x4 acc[8][4];

  // DMA: wave w stages segment w of the 4KB (AV low/high, AK low/high)
  auto dma = [&](int c, int bi) {
    const char* srcb = (w >> 1) ? aktg : avtg;
    f16* dstb = (w >> 1) ? &AK[bi][(w & 1) * 512] : &AV[bi][(w & 1) * 512];
    const char* src = srcb + ((size_t)c << 11) + (w & 1) * 1024 + lane * 16;
    __builtin_amdgcn_global_load_lds((const unsigned int*)src,
                                     (unsigned int*)dstb, 16, 0, 0);
  };

  auto stage_qt = [&](int l0) {        // wave-local transpose stage of Q tile
    const float4* src = (const float4*)(aqb + (size_t)l0 * 8);
    #pragma unroll
    for (int rr = 0; rr < 2; ++rr) {
      int i = rr * 64 + lane;
      float4 q0 = src[i * 2], q1 = src[i * 2 + 1];
      Qt[w][0][i] = q0.x; Qt[w][1][i] = q0.y; Qt[w][2][i] = q0.z; Qt[w][3][i] = q0.w;
      Qt[w][4][i] = q1.x; Qt[w][5][i] = q1.y; Qt[w][6][i] = q1.z; Qt[w][7][i] = q1.w;
    }
  };

  auto unit = [&](int lt, int c, int bi) {
    int dy = 2047 - (lt - c) * 128;
    int zbase = dy - r - a + p * 8 - 112;     // f[dd] <-> d = dd-7; 8-aligned
    f16x8 f[14];
    #pragma unroll
    for (int dd = 0; dd < 14; ++dd)
      f[dd] = *(const f16x8*)&FRS[a][zbase + 16 * dd];
    int ky = r & 7;
    #pragma unroll
    for (int s = 0; s < 4; ++s) {
      f16x8 kf = *(const f16x8*)&AK[bi][ky * 128 + ((s * 32 + p * 8) ^ (ky * 8))];
      #pragma unroll
      for (int nt = 0; nt < 4; ++nt) {
        int vy = nt * 2 + (r >> 3);
        f16x8 vf = *(const f16x8*)&AV[bi][vy * 128 + ((s * 32 + p * 8) ^ (vy * 8))];
        f16x8 bf = vf * kf;                    // v_pk_mul_f16
        #pragma unroll
        for (int mt = 0; mt < 8; ++mt)
          acc[mt][nt] = __builtin_amdgcn_mfma_f32_16x16x32_f16(
              f[7 + 2 * s - mt], bf, acc[mt][nt], 0, 0, 0);
      }
    }
  };

  auto epilogue = [&](int lt) {
    int l0 = lt * 128;
    int hi = r >> 3;
    int n2 = r & 7;
    #pragma unroll
    for (int mt = 0; mt < 8; ++mt) {
      float4 qv[4];
      #pragma unroll
      for (int nt = 0; nt < 4; ++nt)
        qv[nt] = *(const float4*)&Qt[w][nt * 2 + hi][mt * 16 + p * 4];
      #pragma unroll
      for (int reg = 0; reg < 4; ++reg) {
        float pr = qv[0][reg] * acc[mt][0][reg] + qv[1][reg] * acc[mt][1][reg]
                 + qv[2][reg] * acc[mt][2][reg] + qv[3][reg] * acc[mt][3][reg];
        pr += __shfl_xor(pr, 8, 64);
        if (r < 8) {
          int i = mt * 16 + p * 4 + reg;
          out[(((size_t)b * NHH + np) * L_SEQ + (l0 + i)) * HDD + hnb + n2] = pr;
        }
      }
    }
  };

  auto run_pass = [&](int mytile, int NC) {
    dma(0, 0);                         // DMA latency hides under stage_qt
    stage_qt(mytile * 128);
    #pragma unroll
    for (int mt = 0; mt < 8; ++mt)
      #pragma unroll
      for (int nt = 0; nt < 4; ++nt)
        acc[mt][nt] = f32x4{0.f, 0.f, 0.f, 0.f};
    for (int c = 0; c < NC; ++c) {
      __syncthreads();                 // dma(c) landed; units(c-1) all done
      if (c + 1 < NC) dma(c + 1, (c + 1) & 1);   // fly under unit(c)
      if (mytile >= c) unit(mytile, c, c & 1);
      if (mytile == c) epilogue(mytile);
    }
    __syncthreads();                   // bufs reused by next pass
  };

  // pass A: tiles g*4+w (NC = g*4+4); pass B: tiles 15-g*4-w (NC = 16-g*4)
  run_pass(g * 4 + w, g * 4 + 4);
  run_pass(15 - g * 4 - w, 16 - g * 4);
}

// ---------------------------------------------------------------------------
extern "C" void kernel_launch(void* const* d_in, const int* in_sizes, int n_in,
                              void* d_out, int out_size, void* d_ws, size_t ws_size,
                              hipStream_t stream) {
  const float* q_in = (const float*)d_in[0];
  const float* k_in = (const float*)d_in[1];
  const float* v_in = (const float*)d_in[2];
  const float* scw  = (const float*)d_in[3];
  const float* scb  = (const float*)d_in[4];
  const float* Dv   = (const float*)d_in[5];
  const float* w0   = (const float*)d_in[6];
  const float* b0   = (const float*)d_in[7];
  const float* w1   = (const float*)d_in[8];
  const float* b1   = (const float*)d_in[9];
  const float* w2   = (const float*)d_in[10];
  const float* b2   = (const float*)d_in[11];
  const float* fr   = (const float*)d_in[12];
  const float* wf   = (const float*)d_in[13];
  const float* md   = (const float*)d_in[14];

  float* ws   = (float*)d_ws;
  float* filt = ws;                                        // 128*2304 f32
  float* Aq   = ws + (size_t)HDD * FSTRIDE;                // 2*128*2048*8 f32
  f16*   Akt16 = (f16*)(Aq + (size_t)B_SZ * HDD * L_SEQ * NHH);  // 4.19M f16
  f16*   Avt16 = Akt16 + (size_t)B_SZ * HDD * 16 * 1024;         // 4.19M f16

  filter_kernel<<<512, 256, 0, stream>>>(w0, b0, w1, b1, w2, b2, fr, wf, md, Dv, filt);
  shortconv_kernel<<<512, 256, 0, stream>>>(q_in, k_in, v_in, scw, scb, Aq, Akt16, Avt16);
  hyena_main<<<512, 256, 0, stream>>>(Aq, Akt16, Avt16, filt, (float*)d_out);
}